// Round 9
// baseline (85.495 us; speedup 1.0000x reference)
//
#include <hip/hip_runtime.h>
#include <hip/hip_bf16.h>

// Problem constants: B=2, H=8, L=2048, D=64  (fp32 in, fp32 out)
#define BHN    16               // B*H
#define LSEQ   2048
#define DDIM   64
#define CHUNK  128              // l-rows per K1 block
#define NCHUNK (LSEQ / CHUNK)   // 16
#define NPART  (BHN * NCHUNK)   // 256 K1 blocks

typedef unsigned short ushort8 __attribute__((ext_vector_type(8)));
typedef __bf16        bf16x8  __attribute__((ext_vector_type(8)));
typedef float         f32x4   __attribute__((ext_vector_type(4)));

// float -> bf16 bits, round-to-nearest-even
__device__ __forceinline__ unsigned short f2bf(float f) {
    unsigned int u = __float_as_uint(f);
    u = u + 0x7FFFu + ((u >> 16) & 1u);
    return (unsigned short)(u >> 16);
}

union Frag { ushort8 u; bf16x8 b; };

// ---------------------------------------------------------------------------
// K1: M^T[bh] += block-partial (K^T V)^T  via fp32 atomicAdd.
// Per (bh, 128-row chunk) block: streaming K/V reads (no staging), 8x8
// register outer product, XOR-swizzled LDS cross-wave reduce, then 16
// atomicAdds/thread into M (16 KB per bh, zeroed by the memset node).
// ---------------------------------------------------------------------------
__global__ __launch_bounds__(256) void k1_ktv(const float* __restrict__ Km,
                                              const float* __restrict__ Vm,
                                              float* __restrict__ M) {
    __shared__ float R[16384];                    // 64 KB reduce buffer

    const int pid   = blockIdx.x;                 // 0..255
    const int bh    = pid >> 4;
    const int chunk = pid & 15;
    const int t     = threadIdx.x;
    const int w     = t >> 6;
    const int lane  = t & 63;
    const int a     = lane & 7;    // d1 block (x8)
    const int b     = lane >> 3;   // d2 block (x8)

    const float* Kbase = Km + (size_t)bh * LSEQ * DDIM + (size_t)chunk * CHUNK * DDIM;
    const float* Vbase = Vm + (size_t)bh * LSEQ * DDIM + (size_t)chunk * CHUNK * DDIM;

    float acc[8][8];               // acc[j2 (d2)][j1 (d1)]
    #pragma unroll
    for (int i = 0; i < 8; ++i)
        #pragma unroll
        for (int j = 0; j < 8; ++j) acc[i][j] = 0.f;

    // wave w owns rows w*32 .. w*32+31 of the 128-row chunk
    const float* Kw = Kbase + (w * 32) * DDIM;
    const float* Vw = Vbase + (w * 32) * DDIM;

    #pragma unroll 4
    for (int l = 0; l < 32; ++l) {
        float4 k0 = *(const float4*)(Kw + l * DDIM + a * 8);
        float4 k1 = *(const float4*)(Kw + l * DDIM + a * 8 + 4);
        float4 v0 = *(const float4*)(Vw + l * DDIM + b * 8);
        float4 v1 = *(const float4*)(Vw + l * DDIM + b * 8 + 4);
        float kk[8] = {k0.x, k0.y, k0.z, k0.w, k1.x, k1.y, k1.z, k1.w};
        float vv[8] = {v0.x, v0.y, v0.z, v0.w, v1.x, v1.y, v1.z, v1.w};
        #pragma unroll
        for (int j2 = 0; j2 < 8; ++j2)
            #pragma unroll
            for (int j1 = 0; j1 < 8; ++j1)
                acc[j2][j1] = fmaf(kk[j1], vv[j2], acc[j2][j1]);
    }

    // per-wave partial -> LDS, XOR-swizzled so same-j2 stores hit distinct banks
    #pragma unroll
    for (int j2 = 0; j2 < 8; ++j2) {
        int row = b * 8 + j2;            // d2   (row&7 == j2)
        int pc  = (a ^ j2) * 8;          // swizzled d1 col-group
        float* dst = R + w * 4096 + row * 64 + pc;
        *(float4*)(dst)     = float4{acc[j2][0], acc[j2][1], acc[j2][2], acc[j2][3]};
        *(float4*)(dst + 4) = float4{acc[j2][4], acc[j2][5], acc[j2][6], acc[j2][7]};
    }
    __syncthreads();

    // cross-wave reduce + atomic accumulate into M[bh] (coalesced addresses)
    float* Mb = M + (size_t)bh * 4096;
    #pragma unroll
    for (int i = 0; i < 16; ++i) {
        int e   = t + i * 256;
        int row = e >> 6;
        int col = e & 63;
        int pcc = col ^ ((row & 7) << 3);
        int idx = row * 64 + pcc;
        float s = R[idx] + R[4096 + idx] + R[8192 + idx] + R[12288 + idx];
        atomicAdd(&Mb[e], s);
    }
}

// ---------------------------------------------------------------------------
// K3: {load fp32 M[bh] (16 KB, L2-hot) -> swizzled bf16 MT in LDS} +
//     {out = Q @ M via mfma_f32_16x16x32_bf16}.
// 256 blocks x 512 threads; block = (bh, 128 q-rows).
// MT swizzle: group' = group ^ (row&7) -> ds_read_b128 ~conflict-free.
// ---------------------------------------------------------------------------
__global__ __launch_bounds__(512) void k3_qm(const float* __restrict__ Q,
                                             const float* __restrict__ M,
                                             float* __restrict__ Out) {
    __shared__ unsigned short MTs[4096];          // 8 KB: [d2=64][8 groups][8]

    const int bid = blockIdx.x;                   // 0..255
    const int bh  = bid >> 4;
    const int qb  = bid & 15;                     // 128 q-rows per block
    const int t   = threadIdx.x;                  // 0..511

    // ---- phase A: M fp32 -> swizzled bf16 MT in LDS ----
    {
        const f32x4* p4 = (const f32x4*)(M + (size_t)bh * 4096) + t * 2;
        f32x4 s0 = p4[0];
        f32x4 s1 = p4[1];
        const int row = t >> 3;                   // d2
        const int cg  = t & 7;                    // d1 col-group (8 elems)
        ushort8 u = (ushort8){f2bf(s0[0]), f2bf(s0[1]), f2bf(s0[2]), f2bf(s0[3]),
                              f2bf(s1[0]), f2bf(s1[1]), f2bf(s1[2]), f2bf(s1[3])};
        *(ushort8*)(MTs + row * 64 + ((cg ^ (row & 7)) << 3)) = u;
    }
    __syncthreads();

    // ---- phase B: out = Q @ M via mfma_f32_16x16x32_bf16 ----
    {
        const int w    = t >> 6;                  // 0..7
        const int lane = t & 63;
        const int r    = lane & 15;
        const int g    = lane >> 4;
        const int q0   = qb * 128 + w * 16;       // wave's first q row

        const float* Qb = Q + (size_t)bh * LSEQ * DDIM;

        Frag afrag[2];
        #pragma unroll
        for (int s = 0; s < 2; ++s) {
            const float* qp = Qb + (size_t)(q0 + r) * DDIM + s * 32 + g * 8;
            float4 x0 = *(const float4*)qp;
            float4 x1 = *(const float4*)(qp + 4);
            afrag[s].u = (ushort8){f2bf(x0.x), f2bf(x0.y), f2bf(x0.z), f2bf(x0.w),
                                   f2bf(x1.x), f2bf(x1.y), f2bf(x1.z), f2bf(x1.w)};
        }

        float* Ob = Out + (size_t)bh * LSEQ * DDIM;
        #pragma unroll
        for (int nt = 0; nt < 4; ++nt) {
            f32x4 acc = (f32x4){0.f, 0.f, 0.f, 0.f};
            #pragma unroll
            for (int s = 0; s < 2; ++s) {
                const int brow = nt * 16 + r;     // d2
                const int bg   = (s * 4 + g) ^ (r & 7);
                Frag bfrag;
                bfrag.u = *(const ushort8*)(MTs + brow * 64 + bg * 8);
                acc = __builtin_amdgcn_mfma_f32_16x16x32_bf16(afrag[s].b, bfrag.b,
                                                              acc, 0, 0, 0);
            }
            #pragma unroll
            for (int j = 0; j < 4; ++j)
                Ob[(size_t)(q0 + g * 4 + j) * DDIM + nt * 16 + r] = acc[j];
        }
    }
}

// ---------------------------------------------------------------------------
extern "C" void kernel_launch(void* const* d_in, const int* in_sizes, int n_in,
                              void* d_out, int out_size, void* d_ws, size_t ws_size,
                              hipStream_t stream) {
    const float* q = (const float*)d_in[0];
    const float* k = (const float*)d_in[1];
    const float* v = (const float*)d_in[2];
    float* out = (float*)d_out;

    float* M = (float*)d_ws;                      // 16 x 4096 fp32 = 256 KB

    // zero the accumulator (capture-legal memset node; ws is re-poisoned 0xAA
    // before every timed launch, so this must run every call)
    hipMemsetAsync(M, 0, (size_t)BHN * 4096 * sizeof(float), stream);

    k1_ktv<<<NPART, 256, 0, stream>>>(k, v, M);
    k3_qm <<<NPART, 512, 0, stream>>>(q, M, out);
}